// Round 8
// baseline (642.612 us; speedup 1.0000x reference)
//
#include <hip/hip_runtime.h>

using u16 = unsigned short;
typedef int i32x4 __attribute__((ext_vector_type(4)));
typedef int i32x8 __attribute__((ext_vector_type(8)));
typedef float f32x4 __attribute__((ext_vector_type(4)));
typedef float f32x2 __attribute__((ext_vector_type(2)));
typedef float f32x16 __attribute__((ext_vector_type(16)));

#define SC1 0x7F7F7F7F  // e8m0 scale bytes = 2^0 = 1.0 (exact)

// ---------------------------------------------------------------------------
__device__ inline void async16(const void* g, void* l) {
    __builtin_amdgcn_global_load_lds(
        (__attribute__((address_space(1))) void*)(g),
        (__attribute__((address_space(3))) void*)(l),
        16, 0, 0);
}

__device__ inline i32x8 mk8(i32x4 lo, i32x4 hi) {
    return __builtin_shufflevector(lo, hi, 0, 1, 2, 3, 4, 5, 6, 7);
}

// ---------------------------------------------------------------------------
// Quantize per-128-block: scale = amax/448 (fp32), payload fp8 e4m3fn RNE.
// fp8 payload [R][K] row-major; scales transposed [K/128][R].
__global__ void quant_kernel(const float* __restrict__ in,
                             u16* __restrict__ outq,
                             float* __restrict__ outs,
                             long R) {
    long wid = (long)blockIdx.x * 4 + (threadIdx.x >> 6);
    int lane = threadIdx.x & 63;
    if (wid >= R * 32) return;

    float2 v = reinterpret_cast<const float2*>(in + wid * 128)[lane];
    float a = fmaxf(fabsf(v.x), fabsf(v.y));
#pragma unroll
    for (int off = 32; off; off >>= 1) a = fmaxf(a, __shfl_xor(a, off));

    float s = a / 448.0f;
    float qx = v.x / s;
    float qy = v.y / s;
    qx = fminf(fmaxf(qx, -448.0f), 448.0f);
    qy = fminf(fmaxf(qy, -448.0f), 448.0f);

    int pk = __builtin_amdgcn_cvt_pk_fp8_f32(qx, qy, 0, false);
    outq[wid * 64 + lane] = (u16)(pk & 0xFFFF);

    if (lane == 0) {
        long row = wid >> 5, kb = wid & 31;
        outs[kb * R + row] = s;
    }
}

// ---------------------------------------------------------------------------
// fp8 block-scaled GEMM, 256x256 tile, 8 waves (2x4, wave tile 128x64),
// slab = K-block of 128. mfma_scale_f32_32x32x64_f8f6f4, HW scale 1.0;
// fp32 rescale per slab (reference math). 4-phase pipelined schedule.
// R7 BUG FIXED: P4's RD_HEAD(next) overwrote b8/sbv before COMPUTE(3) used
// them (band3 x wrong-slab B). Now RD_HEAD is at P1-top reading the CURRENT
// buffer (landed at prev P4's vmcnt(0)+barrier); P4 only prefetches the
// A-band0 register set (properly double-buffered a0_0/saA vs a0_1/saB).
// LDS: A dbuf 2x32KB @0, B dbuf 2x32KB @64K, sa 2x1KB @128K, sb 2x1KB @130K.
// Swizzle byte^=(row&7)<<4 both-sides.

#define SWZ(x) ((x) ^ ((((x) >> 7) & 7) << 4))

#define FENCE asm volatile("" ::: "memory");
#define BARRIER { __builtin_amdgcn_s_barrier(); FENCE }
#define VMC0 { asm volatile("s_waitcnt vmcnt(0)" ::: "memory"); }

__global__ __launch_bounds__(512, 2) void gemm_fp8(
    const char* __restrict__ Aq, const char* __restrict__ Bq,
    const float* __restrict__ AscaleG, const float* __restrict__ BscaleG,
    float* __restrict__ C, int M, int N) {
    extern __shared__ __align__(16) char smem[];
    const int KBYTES = 4096;

    const int tid = threadIdx.x;
    const int wid = tid >> 6;
    const int lane = tid & 63;
    const int l31 = lane & 31;
    const int lh = lane >> 5;
    const int wr = wid >> 2;
    const int wc = wid & 3;

    int nwg = gridDim.x, bid = blockIdx.x, swz = bid;
    if ((nwg & 7) == 0) swz = (bid & 7) * (nwg >> 3) + (bid >> 3);
    const int nbn = N >> 8;
    const long brow = (long)(swz / nbn) << 8;
    const long bcol = (long)(swz % nbn) << 8;

    const char* Abase = Aq + brow * KBYTES;
    const char* Bbase = Bq + bcol * KBYTES;

    // staging source offsets (inverse-swizzled)
    int aofs[4];
#pragma unroll
    for (int c = 0; c < 4; ++c) {
        int dloc = c * 8192 + wid * 1024 + lane * 16;
        int l = SWZ(dloc);
        aofs[c] = (l >> 7) * KBYTES + (l & 127);
    }

    // swizzled fragment column offsets (row&7 == lane&7 for all our rows)
    int cox[4];
#pragma unroll
    for (int kh = 0; kh < 2; ++kh)
#pragma unroll
        for (int hh = 0; hh < 2; ++hh)
            cox[kh * 2 + hh] =
                (((kh << 6) | (lh << 5) | (hh << 4)) ^ ((lane & 7) << 4));

    int arowb[4], brown[2];
#pragma unroll
    for (int b = 0; b < 4; ++b) arowb[b] = (wr * 128 + b * 32 + l31) << 7;
#pragma unroll
    for (int n = 0; n < 2; ++n) brown[n] = (wc * 64 + n * 32 + l31) << 7;

#define STG_SCALES(kb1) { \
    async16((const char*)AscaleG + ((long)(kb1) * M + brow) * 4 + lane * 16, \
            smem + 131072 + ((kb1) & 1) * 1024); \
    async16((const char*)BscaleG + ((long)(kb1) * N + bcol) * 4 + lane * 16, \
            smem + 133120 + ((kb1) & 1) * 1024); }

#define STG_DATA(kb1, c_) { \
    char* dA_ = smem + ((kb1) & 1) * 32768 + (c_) * 8192 + wid * 1024; \
    async16(Abase + aofs[c_] + (long)(kb1) * 128, dA_); \
    async16(Bbase + aofs[c_] + (long)(kb1) * 128, dA_ + 65536); }

#define RD_HEAD(bufb) { \
    const char* Bb_ = smem + 65536 + (bufb) * 32768; \
    _Pragma("unroll") for (int n_ = 0; n_ < 2; ++n_) \
    _Pragma("unroll") for (int kh_ = 0; kh_ < 2; ++kh_) \
        b8[n_][kh_] = mk8(*(const i32x4*)(Bb_ + brown[n_] + cox[kh_ * 2]), \
                          *(const i32x4*)(Bb_ + brown[n_] + cox[kh_ * 2 + 1])); \
    const float* Sb_ = (const float*)(smem + 133120 + (bufb) * 1024); \
    sbv0 = Sb_[wc * 64 + l31]; \
    sbv1 = Sb_[wc * 64 + 32 + l31]; }

#define RD_BAND(b_, bufb, A0, A1, SA) { \
    const char* Ab_ = smem + (bufb) * 32768; \
    A0 = mk8(*(const i32x4*)(Ab_ + arowb[b_] + cox[0]), \
             *(const i32x4*)(Ab_ + arowb[b_] + cox[1])); \
    A1 = mk8(*(const i32x4*)(Ab_ + arowb[b_] + cox[2]), \
             *(const i32x4*)(Ab_ + arowb[b_] + cox[3])); \
    const float* Sa_ = (const float*)(smem + 131072 + (bufb) * 1024); \
    _Pragma("unroll") for (int i_ = 0; i_ < 4; ++i_) \
        SA[i_] = *(const f32x4*)(Sa_ + wr * 128 + (b_) * 32 + 4 * lh + 8 * i_); }

#define COMPUTE(b_, A0, A1, SA) { \
    __builtin_amdgcn_s_setprio(1); \
    f32x16 t0_ = __builtin_amdgcn_mfma_scale_f32_32x32x64_f8f6f4( \
        A0, b8[0][0], (f32x16)(0.f), 0, 0, 0, SC1, 0, SC1); \
    t0_ = __builtin_amdgcn_mfma_scale_f32_32x32x64_f8f6f4( \
        A1, b8[0][1], t0_, 0, 0, 0, SC1, 0, SC1); \
    f32x16 t1_ = __builtin_amdgcn_mfma_scale_f32_32x32x64_f8f6f4( \
        A0, b8[1][0], (f32x16)(0.f), 0, 0, 0, SC1, 0, SC1); \
    t1_ = __builtin_amdgcn_mfma_scale_f32_32x32x64_f8f6f4( \
        A1, b8[1][1], t1_, 0, 0, 0, SC1, 0, SC1); \
    __builtin_amdgcn_s_setprio(0); \
    _Pragma("unroll") for (int i_ = 0; i_ < 4; ++i_) \
    _Pragma("unroll") for (int j_ = 0; j_ < 4; ++j_) { \
        acc[b_][0][i_ * 4 + j_] = fmaf(t0_[i_ * 4 + j_], SA[i_][j_] * sbv0, \
                                       acc[b_][0][i_ * 4 + j_]); \
        acc[b_][1][i_ * 4 + j_] = fmaf(t1_[i_ * 4 + j_], SA[i_][j_] * sbv1, \
                                       acc[b_][1][i_ * 4 + j_]); } }

    f32x16 acc[4][2];
#pragma unroll
    for (int b = 0; b < 4; ++b)
#pragma unroll
        for (int n = 0; n < 2; ++n)
#pragma unroll
            for (int e = 0; e < 16; ++e) acc[b][n][e] = 0.f;

    i32x8 b8[2][2];
    i32x8 a0_0, a1_0, a0_1, a1_1;
    f32x4 saA[4], saB[4];
    float sbv0, sbv1;

    // ---- prologue: stage slab 0, land it, prefetch band0 registers
    STG_SCALES(0);
    STG_DATA(0, 0); STG_DATA(0, 1); STG_DATA(0, 2); STG_DATA(0, 3);
    VMC0; BARRIER;
    RD_BAND(0, 0, a0_0, a1_0, saA);

    for (int kb = 0; kb < 31; ++kb) {
        const int bufb = kb & 1;
        // P1: read CURRENT slab head (landed); stage scales + chunks 0,1 of
        // slab kb+1; read band1; compute band0 (regs prefetched at prev P4)
        RD_HEAD(bufb);
        STG_SCALES(kb + 1);
        STG_DATA(kb + 1, 0); STG_DATA(kb + 1, 1);
        RD_BAND(1, bufb, a0_1, a1_1, saB);
        COMPUTE(0, a0_0, a1_0, saA);
        BARRIER;
        // P2: stage chunks 2,3; read band2; compute band1
        STG_DATA(kb + 1, 2); STG_DATA(kb + 1, 3);
        RD_BAND(2, bufb, a0_0, a1_0, saA);
        COMPUTE(1, a0_1, a1_1, saB);
        BARRIER;
        // P3: read band3; compute band2
        RD_BAND(3, bufb, a0_1, a1_1, saB);
        COMPUTE(2, a0_0, a1_0, saA);
        BARRIER;
        // P4: land slab kb+1; prefetch its band0 A-registers (a0_0 set —
        // disjoint from COMPUTE(3)'s a0_1/saB/b8); compute band3
        VMC0; BARRIER;
        RD_BAND(0, bufb ^ 1, a0_0, a1_0, saA);
        COMPUTE(3, a0_1, a1_1, saB);
        BARRIER;
    }
    {   // slab 31 (buf1): no staging
        RD_HEAD(1);
        RD_BAND(1, 1, a0_1, a1_1, saB);
        COMPUTE(0, a0_0, a1_0, saA);
        RD_BAND(2, 1, a0_0, a1_0, saA);
        COMPUTE(1, a0_1, a1_1, saB);
        RD_BAND(3, 1, a0_1, a1_1, saB);
        COMPUTE(2, a0_0, a1_0, saA);
        COMPUTE(3, a0_1, a1_1, saB);
    }

    // epilogue: 32x32 C/D layout col = lane&31, row = (e&3)+8*(e>>2)+4*lh
#pragma unroll
    for (int b = 0; b < 4; ++b)
#pragma unroll
        for (int n = 0; n < 2; ++n)
#pragma unroll
            for (int e = 0; e < 16; ++e) {
                long r = brow + wr * 128 + b * 32 + (e & 3) + 8 * (e >> 2) + 4 * lh;
                long cc = bcol + wc * 64 + n * 32 + l31;
                C[r * (long)N + cc] = acc[b][n][e];
            }
#undef STG_SCALES
#undef STG_DATA
#undef RD_HEAD
#undef RD_BAND
#undef COMPUTE
}

// ---------------------------------------------------------------------------
extern "C" void kernel_launch(void* const* d_in, const int* in_sizes, int n_in,
                              void* d_out, int out_size, void* d_ws, size_t ws_size,
                              hipStream_t stream) {
    const float* x = (const float*)d_in[0];   // [B,T,D] fp32, M = B*T
    const float* w = (const float*)d_in[1];   // [O,D] fp32
    float* out = (float*)d_out;               // [M,O] fp32

    const int K = 4096;
    const long M = (long)in_sizes[0] / K;     // 8192
    const long N = (long)in_sizes[1] / K;     // 4096

    u16* Aq = (u16*)d_ws;                     // [M][K] fp8
    u16* Bq = Aq + (size_t)M * K / 2;         // [N][K] fp8
    float* Asc = (float*)(Bq + (size_t)N * K / 2);  // [32][M]
    float* Bsc = Asc + 32 * (size_t)M;              // [32][N]

    const long nblkA = M * 32, nblkB = N * 32;
    quant_kernel<<<dim3((unsigned)((nblkA + 3) / 4)), dim3(256), 0, stream>>>(
        x, Aq, Asc, M);
    quant_kernel<<<dim3((unsigned)((nblkB + 3) / 4)), dim3(256), 0, stream>>>(
        w, Bq, Bsc, N);

    static int smem_set = 0;
    if (!smem_set) {
        hipFuncSetAttribute((const void*)gemm_fp8,
                            hipFuncAttributeMaxDynamicSharedMemorySize, 135168);
        smem_set = 1;
    }
    dim3 grid((unsigned)((M / 256) * (N / 256)));
    gemm_fp8<<<grid, dim3(512), 135168, stream>>>(
        (const char*)Aq, (const char*)Bq, Asc, Bsc, out, (int)M, (int)N);
}

// Round 9
// 274.975 us; speedup vs baseline: 2.3370x; 2.3370x over previous
//
#include <hip/hip_runtime.h>

using u16 = unsigned short;
typedef int i32x4 __attribute__((ext_vector_type(4)));
typedef int i32x8 __attribute__((ext_vector_type(8)));
typedef float f32x4 __attribute__((ext_vector_type(4)));
typedef float f32x2 __attribute__((ext_vector_type(2)));
typedef float f32x16 __attribute__((ext_vector_type(16)));

#define SC1 0x7F7F7F7F  // e8m0 scale bytes = 2^0 = 1.0 (exact)

// ---------------------------------------------------------------------------
__device__ inline void async16(const void* g, void* l) {
    __builtin_amdgcn_global_load_lds(
        (__attribute__((address_space(1))) void*)(g),
        (__attribute__((address_space(3))) void*)(l),
        16, 0, 0);
}

__device__ inline i32x8 mk8(i32x4 lo, i32x4 hi) {
    return __builtin_shufflevector(lo, hi, 0, 1, 2, 3, 4, 5, 6, 7);
}

// ---------------------------------------------------------------------------
// Quantize per-128-block: scale = amax/448 (fp32), payload fp8 e4m3fn RNE.
// fp8 payload [R][K] row-major; scales transposed [K/128][R].
__global__ void quant_kernel(const float* __restrict__ in,
                             u16* __restrict__ outq,
                             float* __restrict__ outs,
                             long R) {
    long wid = (long)blockIdx.x * 4 + (threadIdx.x >> 6);
    int lane = threadIdx.x & 63;
    if (wid >= R * 32) return;

    float2 v = reinterpret_cast<const float2*>(in + wid * 128)[lane];
    float a = fmaxf(fabsf(v.x), fabsf(v.y));
#pragma unroll
    for (int off = 32; off; off >>= 1) a = fmaxf(a, __shfl_xor(a, off));

    float s = a / 448.0f;
    float qx = v.x / s;
    float qy = v.y / s;
    qx = fminf(fmaxf(qx, -448.0f), 448.0f);
    qy = fminf(fmaxf(qy, -448.0f), 448.0f);

    int pk = __builtin_amdgcn_cvt_pk_fp8_f32(qx, qy, 0, false);
    outq[wid * 64 + lane] = (u16)(pk & 0xFFFF);

    if (lane == 0) {
        long row = wid >> 5, kb = wid & 31;
        outs[kb * R + row] = s;
    }
}

// ---------------------------------------------------------------------------
// fp8 block-scaled GEMM, 128x128 tile, 4 waves (2x2, wave tile 64x64),
// slab = K-block of 128. mfma_scale_f32_32x32x64_f8f6f4, HW scale 1.0;
// fp32 per-slab rescale (reference math, fp32 accumulate).
// SIMPLE 2-phase dbuf loop (R6 structure, verified): stage kb+1, compute kb,
// vmcnt(0)+barrier. Overlap comes from 2 INDEPENDENT blocks/CU (LDS 66KB),
// not from intra-block phasing (R8's cross-phase register sets spilled).
// LDS: A dbuf 2x16KB @0, B dbuf 2x16KB @32K, sa 2x512B @64K, sb @65K.
// Swizzle byte^=(row&7)<<4 both-sides.

#define SWZ(x) ((x) ^ ((((x) >> 7) & 7) << 4))

#define FENCE asm volatile("" ::: "memory");
#define BARRIER { __builtin_amdgcn_s_barrier(); FENCE }
#define VMC0 { asm volatile("s_waitcnt vmcnt(0)" ::: "memory"); }

__global__ __launch_bounds__(256, 2) void gemm_fp8(
    const char* __restrict__ Aq, const char* __restrict__ Bq,
    const float* __restrict__ AscaleG, const float* __restrict__ BscaleG,
    float* __restrict__ C, int M, int N) {
    extern __shared__ __align__(16) char smem[];
    const int KBYTES = 4096;

    const int tid = threadIdx.x;
    const int wid = tid >> 6;
    const int lane = tid & 63;
    const int l31 = lane & 31;
    const int lh = lane >> 5;
    const int wr2 = wid >> 1;          // 0..1 (M half)
    const int wc2 = wid & 1;           // 0..1 (N half)

    int nwg = gridDim.x, bid = blockIdx.x, swz = bid;
    if ((nwg & 7) == 0) swz = (bid & 7) * (nwg >> 3) + (bid >> 3);
    const int nbn = N >> 7;            // 32
    const long brow = (long)(swz / nbn) << 7;
    const long bcol = (long)(swz % nbn) << 7;

    const char* Abase = Aq + brow * KBYTES;
    const char* Bbase = Bq + bcol * KBYTES;

    // staging source offsets (inverse-swizzled); dloc = c*4096 + tid*16
    int aofs[4];
#pragma unroll
    for (int c = 0; c < 4; ++c) {
        int dloc = c * 4096 + tid * 16;
        int l = SWZ(dloc);
        aofs[c] = (l >> 7) * KBYTES + (l & 127);
    }

    // swizzled fragment column offsets (row&7 == lane&7 for all our rows)
    int cox[4];
#pragma unroll
    for (int kh = 0; kh < 2; ++kh)
#pragma unroll
        for (int hh = 0; hh < 2; ++hh)
            cox[kh * 2 + hh] =
                (((kh << 6) | (lh << 5) | (hh << 4)) ^ ((lane & 7) << 4));

    int arowb[2], brownn[2];
#pragma unroll
    for (int rb = 0; rb < 2; ++rb) arowb[rb] = (wr2 * 64 + rb * 32 + l31) << 7;
#pragma unroll
    for (int n = 0; n < 2; ++n) brownn[n] = (wc2 * 64 + n * 32 + l31) << 7;

#define STAGE(kb1) { int bufb_ = (kb1) & 1; \
    _Pragma("unroll") for (int c_ = 0; c_ < 4; ++c_) { \
        char* dA_ = smem + bufb_ * 16384 + c_ * 4096 + wid * 1024; \
        async16(Abase + aofs[c_] + (long)(kb1) * 128, dA_); \
        async16(Bbase + aofs[c_] + (long)(kb1) * 128, dA_ + 32768); } \
    if (wid == 0 && lane < 32) \
        async16((const char*)AscaleG + ((long)(kb1) * M + brow) * 4 + lane * 16, \
                smem + 65536 + bufb_ * 512); \
    if (wid == 1 && lane < 32) \
        async16((const char*)BscaleG + ((long)(kb1) * N + bcol) * 4 + lane * 16, \
                smem + 66560 + bufb_ * 512); }

    f32x16 acc[2][2];
#pragma unroll
    for (int rb = 0; rb < 2; ++rb)
#pragma unroll
        for (int n = 0; n < 2; ++n)
#pragma unroll
            for (int e = 0; e < 16; ++e) acc[rb][n][e] = 0.f;

    // prologue
    STAGE(0);
    VMC0; BARRIER;

    for (int kb = 0; kb < 32; ++kb) {
        const int buf = kb & 1;
        if (kb < 31) STAGE(kb + 1);

        const char* Ab = smem + buf * 16384;
        const char* Bb = smem + 32768 + buf * 16384;
        const float* Sa = (const float*)(smem + 65536 + buf * 512);
        const float* Sb = (const float*)(smem + 66560 + buf * 512);

        i32x8 bfr[2][2];  // [n][kh]
#pragma unroll
        for (int n = 0; n < 2; ++n)
#pragma unroll
            for (int kh = 0; kh < 2; ++kh)
                bfr[n][kh] = mk8(*(const i32x4*)(Bb + brownn[n] + cox[kh * 2]),
                                 *(const i32x4*)(Bb + brownn[n] + cox[kh * 2 + 1]));
        float sbv[2];
#pragma unroll
        for (int n = 0; n < 2; ++n) sbv[n] = Sb[wc2 * 64 + n * 32 + l31];

#pragma unroll
        for (int rb = 0; rb < 2; ++rb) {
            i32x8 a0 = mk8(*(const i32x4*)(Ab + arowb[rb] + cox[0]),
                           *(const i32x4*)(Ab + arowb[rb] + cox[1]));
            i32x8 a1 = mk8(*(const i32x4*)(Ab + arowb[rb] + cox[2]),
                           *(const i32x4*)(Ab + arowb[rb] + cox[3]));
            f32x4 sa4[4];
#pragma unroll
            for (int i = 0; i < 4; ++i)
                sa4[i] = *(const f32x4*)(Sa + wr2 * 64 + rb * 32 + 4 * lh + 8 * i);
            __builtin_amdgcn_s_setprio(1);
            f32x16 t0 = __builtin_amdgcn_mfma_scale_f32_32x32x64_f8f6f4(
                a0, bfr[0][0], (f32x16)(0.f), 0, 0, 0, SC1, 0, SC1);
            t0 = __builtin_amdgcn_mfma_scale_f32_32x32x64_f8f6f4(
                a1, bfr[0][1], t0, 0, 0, 0, SC1, 0, SC1);
            f32x16 t1 = __builtin_amdgcn_mfma_scale_f32_32x32x64_f8f6f4(
                a0, bfr[1][0], (f32x16)(0.f), 0, 0, 0, SC1, 0, SC1);
            t1 = __builtin_amdgcn_mfma_scale_f32_32x32x64_f8f6f4(
                a1, bfr[1][1], t1, 0, 0, 0, SC1, 0, SC1);
            __builtin_amdgcn_s_setprio(0);
#pragma unroll
            for (int i = 0; i < 4; ++i)
#pragma unroll
                for (int j = 0; j < 4; ++j) {
                    acc[rb][0][i * 4 + j] = fmaf(t0[i * 4 + j],
                        sa4[i][j] * sbv[0], acc[rb][0][i * 4 + j]);
                    acc[rb][1][i * 4 + j] = fmaf(t1[i * 4 + j],
                        sa4[i][j] * sbv[1], acc[rb][1][i * 4 + j]);
                }
        }

        VMC0; BARRIER;
    }

    // epilogue: 32x32 C/D layout col = lane&31, row = (e&3)+8*(e>>2)+4*lh
#pragma unroll
    for (int rb = 0; rb < 2; ++rb)
#pragma unroll
        for (int n = 0; n < 2; ++n)
#pragma unroll
            for (int e = 0; e < 16; ++e) {
                long r = brow + wr2 * 64 + rb * 32 + (e & 3) + 8 * (e >> 2) + 4 * lh;
                long cc = bcol + wc2 * 64 + n * 32 + l31;
                C[r * (long)N + cc] = acc[rb][n][e];
            }
#undef STAGE
}

// ---------------------------------------------------------------------------
extern "C" void kernel_launch(void* const* d_in, const int* in_sizes, int n_in,
                              void* d_out, int out_size, void* d_ws, size_t ws_size,
                              hipStream_t stream) {
    const float* x = (const float*)d_in[0];   // [B,T,D] fp32, M = B*T
    const float* w = (const float*)d_in[1];   // [O,D] fp32
    float* out = (float*)d_out;               // [M,O] fp32

    const int K = 4096;
    const long M = (long)in_sizes[0] / K;     // 8192
    const long N = (long)in_sizes[1] / K;     // 4096

    u16* Aq = (u16*)d_ws;                     // [M][K] fp8
    u16* Bq = Aq + (size_t)M * K / 2;         // [N][K] fp8
    float* Asc = (float*)(Bq + (size_t)N * K / 2);  // [32][M]
    float* Bsc = Asc + 32 * (size_t)M;              // [32][N]

    const long nblkA = M * 32, nblkB = N * 32;
    quant_kernel<<<dim3((unsigned)((nblkA + 3) / 4)), dim3(256), 0, stream>>>(
        x, Aq, Asc, M);
    quant_kernel<<<dim3((unsigned)((nblkB + 3) / 4)), dim3(256), 0, stream>>>(
        w, Bq, Bsc, N);

    static int smem_set = 0;
    if (!smem_set) {
        hipFuncSetAttribute((const void*)gemm_fp8,
                            hipFuncAttributeMaxDynamicSharedMemorySize, 67584);
        smem_set = 1;
    }
    dim3 grid((unsigned)((M / 128) * (N / 128)));
    gemm_fp8<<<grid, dim3(256), 67584, stream>>>(
        (const char*)Aq, (const char*)Bq, Asc, Bsc, out, (int)M, (int)N);
}